// Round 4
// baseline (457.472 us; speedup 1.0000x reference)
//
#include <hip/hip_runtime.h>

namespace {

constexpr int B = 16, S = 1024, M = 4096, C = 768, D = 256;
constexpr int N = B * S;  // flattened (b,s) rows = 16384

typedef __attribute__((ext_vector_type(8))) short bf16x8;
typedef __attribute__((ext_vector_type(4))) float f32x4;

__device__ inline ushort f2bf(float f) {
  uint u = __float_as_uint(f);
  uint r = (u + 0x7FFFu + ((u >> 16) & 1u)) >> 16;
  return (ushort)r;
}

// async global->LDS, 16B per lane. LDS dest is wave-uniform base + lane*16.
__device__ __forceinline__ void g2lds16(const ushort* g, ushort* l) {
  __builtin_amdgcn_global_load_lds(
      (const __attribute__((address_space(1))) uint*)g,
      (__attribute__((address_space(3))) uint*)l, 16, 0, 0);
}

// ---------------------------------------------------------------------------
// Kernel 1: nearest-neighbor argmin (bit-exact reference distance formula).
// ---------------------------------------------------------------------------
__global__ __launch_bounds__(256)
void nn_kernel(const float* __restrict__ xyz, const float* __restrict__ p,
               int* __restrict__ idx_out) {
  const int b = blockIdx.y;
  const int t = threadIdx.x;
  const int seed = blockIdx.x * 16 + (t >> 4);
  const int l16 = t & 15;

  const float sx = xyz[((size_t)b * S + seed) * 3 + 0];
  const float sy = xyz[((size_t)b * S + seed) * 3 + 1];
  const float sz = xyz[((size_t)b * S + seed) * 3 + 2];
  const float ss = __fadd_rn(__fadd_rn(__fmul_rn(sx, sx), __fmul_rn(sy, sy)),
                             __fmul_rn(sz, sz));

  __shared__ float4 pt[256];

  float best = 3.4028235e38f;
  int besti = 0;
  const float* pb = p + (size_t)b * M * 3;

  for (int m0 = 0; m0 < M; m0 += 256) {
    __syncthreads();
    {
      const float a0 = pb[(size_t)(m0 + t) * 3 + 0];
      const float a1 = pb[(size_t)(m0 + t) * 3 + 1];
      const float a2 = pb[(size_t)(m0 + t) * 3 + 2];
      const float pp = __fadd_rn(__fadd_rn(__fmul_rn(a0, a0), __fmul_rn(a1, a1)),
                                 __fmul_rn(a2, a2));
      pt[t] = make_float4(a0, a1, a2, pp);
    }
    __syncthreads();
    #pragma unroll 4
    for (int j = l16; j < 256; j += 16) {
      const float4 q = pt[j];
      float dot = __fmul_rn(sx, q.x);
      dot = __fadd_rn(dot, __fmul_rn(sy, q.y));
      dot = __fadd_rn(dot, __fmul_rn(sz, q.z));
      const float d2 = __fadd_rn(__fsub_rn(ss, __fmul_rn(2.0f, dot)), q.w);
      const int mi = m0 + j;
      if (d2 < best || (d2 == best && mi < besti)) { best = d2; besti = mi; }
    }
  }
  #pragma unroll
  for (int off = 8; off >= 1; off >>= 1) {
    const float ob = __shfl_xor(best, off, 16);
    const int   oi = __shfl_xor(besti, off, 16);
    if (ob < best || (ob == best && oi < besti)) { best = ob; besti = oi; }
  }
  if (l16 == 0) idx_out[b * S + seed] = besti;
}

// ---------------------------------------------------------------------------
// Kernel 1b: per-batch bitonic sort of (idx, s) by idx.
// ---------------------------------------------------------------------------
__global__ __launch_bounds__(512)
void sort_kernel(const int* __restrict__ idx, int* __restrict__ sIdx,
                 int* __restrict__ sS) {
  const int b = blockIdx.x;
  const int t = threadIdx.x;
  __shared__ int key[1024];
  __shared__ int val[1024];
  key[t] = idx[b * S + t];             val[t] = t;
  key[t + 512] = idx[b * S + t + 512]; val[t + 512] = t + 512;
  __syncthreads();
  for (int k = 2; k <= 1024; k <<= 1) {
    for (int j = k >> 1; j > 0; j >>= 1) {
      #pragma unroll 2
      for (int i = t; i < 1024; i += 512) {
        const int p = i ^ j;
        if (p > i) {
          const bool up = ((i & k) == 0);
          const int ki = key[i], kp = key[p];
          if ((ki > kp) == up) {
            key[i] = kp; key[p] = ki;
            const int tv = val[i]; val[i] = val[p]; val[p] = tv;
          }
        }
      }
      __syncthreads();
    }
  }
  sIdx[b * S + t] = key[t];             sS[b * S + t] = val[t];
  sIdx[b * S + t + 512] = key[t + 512]; sS[b * S + t + 512] = val[t + 512];
}

// ---------------------------------------------------------------------------
// Kernel 2: coalesced transpose-gather. Block (mtile of 64, b): reads
// f_last[b][c][m0:m0+64] fully coalesced, LDS-transpose, scatters columns
// needed by seeds whose idx falls in [m0, m0+64) (contiguous sorted-rank
// range via binary search) to tmp fp32 [b*S + s][C].
// ---------------------------------------------------------------------------
__global__ __launch_bounds__(256)
void gatherT_kernel(const float* __restrict__ f, const int* __restrict__ sIdx,
                    const int* __restrict__ sS, float* __restrict__ tmp) {
  const int b = blockIdx.y;
  const int m0 = blockIdx.x * 64;
  const int t = threadIdx.x;
  __shared__ float tile[64][65];
  __shared__ int bound[2];

  if (t < 2) {
    const int target = m0 + (t ? 64 : 0);
    int lo = 0, hi = S;
    while (lo < hi) {
      const int mid = (lo + hi) >> 1;
      if (sIdx[b * S + mid] < target) lo = mid + 1; else hi = mid;
    }
    bound[t] = lo;
  }
  __syncthreads();
  const int lo = bound[0];
  const int cnt = bound[1] - bound[0];
  if (cnt == 0) return;  // block-uniform exit

  const float* fb = f + (size_t)b * C * M + m0;
  const int wv = t >> 6;     // wave id 0..3
  const int ml = t & 63;

  for (int cc = 0; cc < 12; ++cc) {
    __syncthreads();
    const int c0 = cc * 64;
    #pragma unroll
    for (int q = 0; q < 16; ++q) {
      const int cl = q * 4 + wv;
      tile[cl][ml] = fb[(size_t)(c0 + cl) * M + ml];
    }
    __syncthreads();
    for (int i0 = 0; i0 < cnt; i0 += 4) {
      const int i = i0 + wv;
      if (i < cnt) {
        const int r = lo + i;
        const int mloc = sIdx[b * S + r] - m0;
        const int s = sS[b * S + r];
        tmp[((size_t)b * S + s) * C + c0 + ml] = tile[ml][mloc];
      }
    }
  }
}

// ---------------------------------------------------------------------------
// Kernel 3: LayerNorm over C on tmp fp32 rows -> xln bf16 [n][C].
// ---------------------------------------------------------------------------
__global__ __launch_bounds__(256)
void ln_kernel(const float* __restrict__ tmp,
               const float* __restrict__ gamma, const float* __restrict__ beta,
               ushort* __restrict__ xln) {
  const int n = blockIdx.y * 1024 + blockIdx.x;
  const int t = threadIdx.x;
  const float* row = tmp + (size_t)n * C;
  const float v0 = row[t], v1 = row[t + 256], v2 = row[t + 512];

  __shared__ float red[4];
  __shared__ float stats[2];
  const int wave = t >> 6;

  float ps = v0 + v1 + v2;
  #pragma unroll
  for (int off = 32; off >= 1; off >>= 1) ps += __shfl_xor(ps, off);
  if ((t & 63) == 0) red[wave] = ps;
  __syncthreads();
  if (t == 0) stats[0] = (red[0] + red[1] + red[2] + red[3]) * (1.0f / 768.0f);
  __syncthreads();
  const float mu = stats[0];

  const float d0 = v0 - mu, d1 = v1 - mu, d2 = v2 - mu;
  float pv = d0 * d0 + d1 * d1 + d2 * d2;
  #pragma unroll
  for (int off = 32; off >= 1; off >>= 1) pv += __shfl_xor(pv, off);
  if ((t & 63) == 0) red[wave] = pv;
  __syncthreads();
  if (t == 0) {
    const float var = (red[0] + red[1] + red[2] + red[3]) * (1.0f / 768.0f);
    stats[1] = 1.0f / sqrtf(var + 1e-5f);
  }
  __syncthreads();
  const float rs = stats[1];

  ushort* ob = xln + (size_t)n * C;
  ob[t      ] = f2bf((d0 * rs) * gamma[t      ] + beta[t      ]);
  ob[t + 256] = f2bf((d1 * rs) * gamma[t + 256] + beta[t + 256]);
  ob[t + 512] = f2bf((d2 * rs) * gamma[t + 512] + beta[t + 512]);
}

// ---------------------------------------------------------------------------
// Kernel 4: transpose+convert seed_features [B][D][S] f32 -> fused[n][0:256] bf16
// ---------------------------------------------------------------------------
__global__ __launch_bounds__(256)
void transpose_sf_kernel(const float* __restrict__ sf, ushort* __restrict__ fused) {
  const int b = blockIdx.z;
  const int d0 = blockIdx.y * 64;
  const int s0 = blockIdx.x * 64;
  const int t = threadIdx.x;
  __shared__ float tile[64][68];

  const float* inb = sf + ((size_t)b * D + d0) * S + s0;
  #pragma unroll
  for (int q = 0; q < 4; ++q) {
    const int rr = (t >> 4) + q * 16;
    const int c4 = (t & 15) * 4;
    const float4 v = *(const float4*)&inb[(size_t)rr * S + c4];
    *(float4*)&tile[rr][c4] = v;
  }
  __syncthreads();
  #pragma unroll
  for (int q = 0; q < 4; ++q) {
    const int srow = (t >> 4) + q * 16;
    const int dc = (t & 15) * 4;
    ushort4 o;
    o.x = f2bf(tile[dc + 0][srow]);
    o.y = f2bf(tile[dc + 1][srow]);
    o.z = f2bf(tile[dc + 2][srow]);
    o.w = f2bf(tile[dc + 3][srow]);
    *(ushort4*)&fused[((size_t)b * S + s0 + srow) * 512 + d0 + dc] = o;
  }
}

// ---------------------------------------------------------------------------
// Kernel 5: convert the three weight matrices f32 -> bf16 (layout kept [O][K])
// ---------------------------------------------------------------------------
__global__ __launch_bounds__(256)
void convert_w_kernel(const float* __restrict__ w0, int n0, ushort* __restrict__ o0,
                      const float* __restrict__ w1, int n1, ushort* __restrict__ o1,
                      const float* __restrict__ w2, int n2, ushort* __restrict__ o2) {
  const int which = blockIdx.y;
  const float* src = which == 0 ? w0 : which == 1 ? w1 : w2;
  ushort* dst = which == 0 ? o0 : which == 1 ? o1 : o2;
  const int n = which == 0 ? n0 : which == 1 ? n1 : n2;
  const int i = (blockIdx.x * 256 + threadIdx.x) * 4;
  if (i < n) {
    const float4 v = *(const float4*)&src[i];
    ushort4 o;
    o.x = f2bf(v.x); o.y = f2bf(v.y); o.z = f2bf(v.z); o.w = f2bf(v.w);
    *(ushort4*)&dst[i] = o;
  }
}

// ---------------------------------------------------------------------------
// Kernel 6: bf16 MFMA GEMM, m97-style global_load_lds staging.
// out[n,o] = act( sum_k W[o,k] X[n,k] + bias[o] ),  n = flattened (b,s).
// Tile 128o x 64s, BK=32, 4 waves (wave = 64o x 32s, 4x2 of 16x16x32 MFMA).
// LDS rows are unpadded 64B (required by global_load_lds); bank conflicts on
// the b128 fragment reads are broken by XOR-swizzling the *global* chunk each
// lane fetches: LDS[row][j] holds global chunk j^(row&3)  (8-way -> 2-way).
// outMode 0: bf16 [n][ldOut] at column colOff (+ReLU). outMode 1: fp32 [B][O][S].
// ---------------------------------------------------------------------------
__global__ __launch_bounds__(256, 2)
void gemm_bf16_kernel(const ushort* __restrict__ W, int K, int O,
                      const ushort* __restrict__ X,
                      const float* __restrict__ bias,
                      void* __restrict__ out, int outMode, int ldOut, int colOff,
                      int relu) {
  const int n0 = blockIdx.x * 64;
  const int o0 = blockIdx.y * 128;
  const int t = threadIdx.x;
  const int w = t >> 6;
  const int lane = t & 63;
  const int l16 = lane & 15;
  const int quad = lane >> 4;
  const int wo = w >> 1;    // o-half (64 each)
  const int wsd = w & 1;    // s-half (32 each)

  __shared__ ushort Wt[128 * 32];   // [row][32k], 64B rows, unpadded
  __shared__ ushort Xt[64 * 32];
  __shared__ float biasS[128];
  if (t < 128) biasS[t] = bias[o0 + t];

  f32x4 acc[4][2];
  const f32x4 z = {0.f, 0.f, 0.f, 0.f};
  #pragma unroll
  for (int of = 0; of < 4; ++of) { acc[of][0] = z; acc[of][1] = z; }

  const int srow = lane >> 2;     // 0..15 within an issue
  const int chk = lane & 3;       // 16B chunk slot this lane deposits

  for (int c0 = 0; c0 < K; c0 += 32) {
    __syncthreads();
    // stage W: wave w covers rows [w*32, w*32+32), 2 issues of 16 rows
    #pragma unroll
    for (int q = 0; q < 2; ++q) {
      const int r = w * 32 + q * 16 + srow;
      const int cc = chk ^ (r & 3);
      g2lds16(&W[(size_t)(o0 + r) * K + c0 + cc * 8], &Wt[(w * 32 + q * 16) * 32]);
    }
    // stage X: wave w covers rows [w*16, w*16+16), 1 issue
    {
      const int r = w * 16 + srow;
      const int cc = chk ^ (r & 3);
      g2lds16(&X[(size_t)(n0 + r) * K + c0 + cc * 8], &Xt[(w * 16) * 32]);
    }
    __syncthreads();   // vmcnt(0) drain + barrier

    bf16x8 bfr[2];
    #pragma unroll
    for (int sf = 0; sf < 2; ++sf) {
      const int sr = wsd * 32 + sf * 16 + l16;
      bfr[sf] = *(const bf16x8*)&Xt[sr * 32 + ((quad ^ (sr & 3)) * 8)];
    }
    #pragma unroll
    for (int of = 0; of < 4; ++of) {
      const int orr = wo * 64 + of * 16 + l16;
      const bf16x8 afr = *(const bf16x8*)&Wt[orr * 32 + ((quad ^ (orr & 3)) * 8)];
      acc[of][0] = __builtin_amdgcn_mfma_f32_16x16x32_bf16(afr, bfr[0], acc[of][0], 0, 0, 0);
      acc[of][1] = __builtin_amdgcn_mfma_f32_16x16x32_bf16(afr, bfr[1], acc[of][1], 0, 0, 0);
    }
  }

  // epilogue: lane holds D[o = of*16 + quad*4 + r][n-col = sf*16 + l16]
  if (outMode == 0) {
    ushort* ob = (ushort*)out;
    #pragma unroll
    for (int of = 0; of < 4; ++of) {
      #pragma unroll
      for (int sf = 0; sf < 2; ++sf) {
        const int n = n0 + wsd * 32 + sf * 16 + l16;
        const int ol = wo * 64 + of * 16 + quad * 4;
        float v0 = acc[of][sf].x + biasS[ol + 0];
        float v1 = acc[of][sf].y + biasS[ol + 1];
        float v2 = acc[of][sf].z + biasS[ol + 2];
        float v3 = acc[of][sf].w + biasS[ol + 3];
        if (relu) {
          v0 = fmaxf(v0, 0.f); v1 = fmaxf(v1, 0.f);
          v2 = fmaxf(v2, 0.f); v3 = fmaxf(v3, 0.f);
        }
        ushort4 st;
        st.x = f2bf(v0); st.y = f2bf(v1); st.z = f2bf(v2); st.w = f2bf(v3);
        *(ushort4*)&ob[(size_t)n * ldOut + colOff + o0 + ol] = st;
      }
    }
  } else {
    float* o32 = (float*)out;
    #pragma unroll
    for (int of = 0; of < 4; ++of) {
      #pragma unroll
      for (int sf = 0; sf < 2; ++sf) {
        const int n = n0 + wsd * 32 + sf * 16 + l16;
        const int ol = wo * 64 + of * 16 + quad * 4;
        const int bb = n >> 10, s = n & 1023;
        const float vr[4] = {acc[of][sf].x, acc[of][sf].y, acc[of][sf].z, acc[of][sf].w};
        #pragma unroll
        for (int r = 0; r < 4; ++r) {
          const int o = o0 + ol + r;
          o32[((size_t)bb * O + o) * S + s] = vr[r] + biasS[ol + r];
        }
      }
    }
  }
}

}  // namespace

extern "C" void kernel_launch(void* const* d_in, const int* in_sizes, int n_in,
                              void* d_out, int out_size, void* d_ws, size_t ws_size,
                              hipStream_t stream) {
  const float* seed_xyz  = (const float*)d_in[0];
  const float* p_last    = (const float*)d_in[1];
  const float* f_last    = (const float*)d_in[2];
  const float* seed_feat = (const float*)d_in[3];
  const float* ln_gamma  = (const float*)d_in[4];
  const float* ln_beta   = (const float*)d_in[5];
  const float* proj_w    = (const float*)d_in[6];
  const float* proj_b    = (const float*)d_in[7];
  const float* mlp_w1    = (const float*)d_in[8];
  const float* mlp_b1    = (const float*)d_in[9];
  const float* mlp_w2    = (const float*)d_in[10];
  const float* mlp_b2    = (const float*)d_in[11];
  float* out = (float*)d_out;

  // workspace layout:
  //   0      +64KB   idx
  //   64KB   +64KB   sIdx
  //   128KB  +64KB   sS
  //   256KB  +384KB  proj_w bf16
  //   640KB  +512KB  mlp_w1 bf16
  //   1152KB +256KB  mlp_w2 bf16
  //   2MB    +48MB   tmp   fp32 [16384][768]  (gathered, pre-LN)
  //   50MB   +24MB   xln   bf16 [16384][768]
  //   74MB   +16MB   fused bf16 [16384][512]
  //   90MB   +16MB   h     bf16 [16384][512]
  char* ws = (char*)d_ws;
  int*    idx   = (int*)(ws);
  int*    sIdx  = (int*)(ws + (64 << 10));
  int*    sS    = (int*)(ws + (128 << 10));
  ushort* wp_bf = (ushort*)(ws + (256 << 10));
  ushort* w1_bf = (ushort*)(ws + (640 << 10));
  ushort* w2_bf = (ushort*)(ws + (1152 << 10));
  float*  tmp   = (float*)(ws + (2ull << 20));
  ushort* xln   = (ushort*)(ws + (50ull << 20));
  ushort* fused = (ushort*)(ws + (74ull << 20));
  ushort* hbuf  = (ushort*)(ws + (90ull << 20));

  nn_kernel<<<dim3(S / 16, B), 256, 0, stream>>>(seed_xyz, p_last, idx);
  sort_kernel<<<dim3(B), 512, 0, stream>>>(idx, sIdx, sS);

  gatherT_kernel<<<dim3(M / 64, B), 256, 0, stream>>>(f_last, sIdx, sS, tmp);
  ln_kernel<<<dim3(1024, B), 256, 0, stream>>>(tmp, ln_gamma, ln_beta, xln);

  transpose_sf_kernel<<<dim3(S / 64, D / 64, B), 256, 0, stream>>>(seed_feat, fused);
  convert_w_kernel<<<dim3(256, 3), 256, 0, stream>>>(
      proj_w, D * C, wp_bf, mlp_w1, 512 * 512, w1_bf, mlp_w2, 256 * 512, w2_bf);

  // proj = relu(proj_w @ xln + b) -> fused[:, 256:512]
  gemm_bf16_kernel<<<dim3(N / 64, 256 / 128), 256, 0, stream>>>(
      wp_bf, C, 256, xln, proj_b, fused, 0, 512, 256, 1);

  // h = relu(mlp_w1 @ fused + b1) -> hbuf
  gemm_bf16_kernel<<<dim3(N / 64, 512 / 128), 256, 0, stream>>>(
      w1_bf, 512, 512, fused, mlp_b1, hbuf, 0, 512, 0, 1);

  // out = mlp_w2 @ h + b2 -> fp32 [B][256][S]
  gemm_bf16_kernel<<<dim3(N / 64, 256 / 128), 256, 0, stream>>>(
      w2_bf, 512, 256, hbuf, mlp_b2, out, 1, 0, 0, 0);
}

// Round 5
// 450.243 us; speedup vs baseline: 1.0161x; 1.0161x over previous
//
#include <hip/hip_runtime.h>

namespace {

constexpr int B = 16, S = 1024, M = 4096, C = 768, D = 256;
constexpr int N = B * S;  // 16384 rows

typedef __attribute__((ext_vector_type(8))) short bf16x8;
typedef __attribute__((ext_vector_type(4))) float f32x4;

__device__ inline ushort f2bf(float f) {
  uint u = __float_as_uint(f);
  uint r = (u + 0x7FFFu + ((u >> 16) & 1u)) >> 16;
  return (ushort)r;
}
__device__ inline float bf2f(ushort u) {
  return __uint_as_float(((uint)u) << 16);
}

// async global->LDS, 16B per lane; LDS dest = wave-uniform base + lane*16.
__device__ __forceinline__ void g2lds16(const ushort* g, ushort* l) {
  __builtin_amdgcn_global_load_lds(
      (const __attribute__((address_space(1))) uint*)g,
      (__attribute__((address_space(3))) uint*)l, 16, 0, 0);
}

// Stage 16 rows [r0, r0+16) of src (row stride ldk ushorts, k-window c0) into
// dst (32-ushort rows, chunk j stored at slot j^(row&3)). One wave issue.
__device__ __forceinline__ void stage16(const ushort* __restrict__ src, int ldk,
                                        int r0, int c0, ushort* dst, int lane) {
  const int sr = lane >> 2, ck = lane & 3;
  const int r = r0 + sr;
  const int cc = ck ^ (r & 3);
  g2lds16(&src[(size_t)r * ldk + c0 + cc * 8], dst + r0 * 32);
}

// Chunk-swizzled LDS layout for 32-row x (nch=32 chunk) matrices:
// chunk c of row r lives at slot c^(r&7). ushort offset:
__device__ __forceinline__ int swz32(int row, int ch) {
  return row * 256 + (ch ^ (row & 7)) * 8;
}

// ---------------------------------------------------------------------------
// Kernel 1: nearest-neighbor argmin (bit-exact reference distance formula).
// ---------------------------------------------------------------------------
__global__ __launch_bounds__(256)
void nn_kernel(const float* __restrict__ xyz, const float* __restrict__ p,
               int* __restrict__ idx_out) {
  const int b = blockIdx.y;
  const int t = threadIdx.x;
  const int seed = blockIdx.x * 16 + (t >> 4);
  const int l16 = t & 15;

  const float sx = xyz[((size_t)b * S + seed) * 3 + 0];
  const float sy = xyz[((size_t)b * S + seed) * 3 + 1];
  const float sz = xyz[((size_t)b * S + seed) * 3 + 2];
  const float ss = __fadd_rn(__fadd_rn(__fmul_rn(sx, sx), __fmul_rn(sy, sy)),
                             __fmul_rn(sz, sz));

  __shared__ float4 pt[256];

  float best = 3.4028235e38f;
  int besti = 0;
  const float* pb = p + (size_t)b * M * 3;

  for (int m0 = 0; m0 < M; m0 += 256) {
    __syncthreads();
    {
      const float a0 = pb[(size_t)(m0 + t) * 3 + 0];
      const float a1 = pb[(size_t)(m0 + t) * 3 + 1];
      const float a2 = pb[(size_t)(m0 + t) * 3 + 2];
      const float pp = __fadd_rn(__fadd_rn(__fmul_rn(a0, a0), __fmul_rn(a1, a1)),
                                 __fmul_rn(a2, a2));
      pt[t] = make_float4(a0, a1, a2, pp);
    }
    __syncthreads();
    #pragma unroll 4
    for (int j = l16; j < 256; j += 16) {
      const float4 q = pt[j];
      float dot = __fmul_rn(sx, q.x);
      dot = __fadd_rn(dot, __fmul_rn(sy, q.y));
      dot = __fadd_rn(dot, __fmul_rn(sz, q.z));
      const float d2 = __fadd_rn(__fsub_rn(ss, __fmul_rn(2.0f, dot)), q.w);
      const int mi = m0 + j;
      if (d2 < best || (d2 == best && mi < besti)) { best = d2; besti = mi; }
    }
  }
  #pragma unroll
  for (int off = 8; off >= 1; off >>= 1) {
    const float ob = __shfl_xor(best, off, 16);
    const int   oi = __shfl_xor(besti, off, 16);
    if (ob < best || (ob == best && oi < besti)) { best = ob; besti = oi; }
  }
  if (l16 == 0) idx_out[b * S + seed] = besti;
}

// ---------------------------------------------------------------------------
// Kernel 1b: per-batch bitonic sort of (idx, s) by idx.
// ---------------------------------------------------------------------------
__global__ __launch_bounds__(512)
void sort_kernel(const int* __restrict__ idx, int* __restrict__ sIdx,
                 int* __restrict__ sS) {
  const int b = blockIdx.x;
  const int t = threadIdx.x;
  __shared__ int key[1024];
  __shared__ int val[1024];
  key[t] = idx[b * S + t];             val[t] = t;
  key[t + 512] = idx[b * S + t + 512]; val[t + 512] = t + 512;
  __syncthreads();
  for (int k = 2; k <= 1024; k <<= 1) {
    for (int j = k >> 1; j > 0; j >>= 1) {
      #pragma unroll 2
      for (int i = t; i < 1024; i += 512) {
        const int p = i ^ j;
        if (p > i) {
          const bool up = ((i & k) == 0);
          const int ki = key[i], kp = key[p];
          if ((ki > kp) == up) {
            key[i] = kp; key[p] = ki;
            const int tv = val[i]; val[i] = val[p]; val[p] = tv;
          }
        }
      }
      __syncthreads();
    }
  }
  sIdx[b * S + t] = key[t];             sS[b * S + t] = val[t];
  sIdx[b * S + t + 512] = key[t + 512]; sS[b * S + t + 512] = val[t + 512];
}

// ---------------------------------------------------------------------------
// Kernel 2: coalesced transpose-gather -> tmp bf16 [n][C].
// ---------------------------------------------------------------------------
__global__ __launch_bounds__(256)
void gatherT_kernel(const float* __restrict__ f, const int* __restrict__ sIdx,
                    const int* __restrict__ sS, ushort* __restrict__ tmp) {
  const int b = blockIdx.y;
  const int m0 = blockIdx.x * 64;
  const int t = threadIdx.x;
  __shared__ float tile[64][65];
  __shared__ int bound[2];

  if (t < 2) {
    const int target = m0 + (t ? 64 : 0);
    int lo = 0, hi = S;
    while (lo < hi) {
      const int mid = (lo + hi) >> 1;
      if (sIdx[b * S + mid] < target) lo = mid + 1; else hi = mid;
    }
    bound[t] = lo;
  }
  __syncthreads();
  const int lo = bound[0];
  const int cnt = bound[1] - bound[0];
  if (cnt == 0) return;

  const float* fb = f + (size_t)b * C * M + m0;
  const int wv = t >> 6;
  const int ml = t & 63;

  for (int cc = 0; cc < 12; ++cc) {
    __syncthreads();
    const int c0 = cc * 64;
    #pragma unroll
    for (int q = 0; q < 16; ++q) {
      const int cl = q * 4 + wv;
      tile[cl][ml] = fb[(size_t)(c0 + cl) * M + ml];
    }
    __syncthreads();
    for (int i0 = 0; i0 < cnt; i0 += 4) {
      const int i = i0 + wv;
      if (i < cnt) {
        const int r = lo + i;
        const int mloc = sIdx[b * S + r] - m0;
        const int s = sS[b * S + r];
        tmp[((size_t)b * S + s) * C + c0 + ml] = f2bf(tile[ml][mloc]);
      }
    }
  }
}

// ---------------------------------------------------------------------------
// Kernel 3: LayerNorm over C (bf16 in) -> xln bf16 [n][C].
// ---------------------------------------------------------------------------
__global__ __launch_bounds__(256)
void ln_kernel(const ushort* __restrict__ tmp,
               const float* __restrict__ gamma, const float* __restrict__ beta,
               ushort* __restrict__ xln) {
  const int n = blockIdx.y * 1024 + blockIdx.x;
  const int t = threadIdx.x;
  const ushort* row = tmp + (size_t)n * C;
  const float v0 = bf2f(row[t]), v1 = bf2f(row[t + 256]), v2 = bf2f(row[t + 512]);

  __shared__ float red[4];
  __shared__ float stats[2];
  const int wave = t >> 6;

  float ps = v0 + v1 + v2;
  #pragma unroll
  for (int off = 32; off >= 1; off >>= 1) ps += __shfl_xor(ps, off);
  if ((t & 63) == 0) red[wave] = ps;
  __syncthreads();
  if (t == 0) stats[0] = (red[0] + red[1] + red[2] + red[3]) * (1.0f / 768.0f);
  __syncthreads();
  const float mu = stats[0];

  const float d0 = v0 - mu, d1 = v1 - mu, d2 = v2 - mu;
  float pv = d0 * d0 + d1 * d1 + d2 * d2;
  #pragma unroll
  for (int off = 32; off >= 1; off >>= 1) pv += __shfl_xor(pv, off);
  if ((t & 63) == 0) red[wave] = pv;
  __syncthreads();
  if (t == 0) {
    const float var = (red[0] + red[1] + red[2] + red[3]) * (1.0f / 768.0f);
    stats[1] = 1.0f / sqrtf(var + 1e-5f);
  }
  __syncthreads();
  const float rs = stats[1];

  ushort* ob = xln + (size_t)n * C;
  ob[t      ] = f2bf((d0 * rs) * gamma[t      ] + beta[t      ]);
  ob[t + 256] = f2bf((d1 * rs) * gamma[t + 256] + beta[t + 256]);
  ob[t + 512] = f2bf((d2 * rs) * gamma[t + 512] + beta[t + 512]);
}

// ---------------------------------------------------------------------------
// Kernel 4: transpose+convert seed_features [B][D][S] f32 -> seedT bf16 [n][256]
// ---------------------------------------------------------------------------
__global__ __launch_bounds__(256)
void transpose_sf_kernel(const float* __restrict__ sf, ushort* __restrict__ seedT) {
  const int b = blockIdx.z;
  const int d0 = blockIdx.y * 64;
  const int s0 = blockIdx.x * 64;
  const int t = threadIdx.x;
  __shared__ float tile[64][68];

  const float* inb = sf + ((size_t)b * D + d0) * S + s0;
  #pragma unroll
  for (int q = 0; q < 4; ++q) {
    const int rr = (t >> 4) + q * 16;
    const int c4 = (t & 15) * 4;
    const float4 v = *(const float4*)&inb[(size_t)rr * S + c4];
    *(float4*)&tile[rr][c4] = v;
  }
  __syncthreads();
  #pragma unroll
  for (int q = 0; q < 4; ++q) {
    const int srow = (t >> 4) + q * 16;
    const int dc = (t & 15) * 4;
    ushort4 o;
    o.x = f2bf(tile[dc + 0][srow]);
    o.y = f2bf(tile[dc + 1][srow]);
    o.z = f2bf(tile[dc + 2][srow]);
    o.w = f2bf(tile[dc + 3][srow]);
    *(ushort4*)&seedT[((size_t)b * S + s0 + srow) * 256 + d0 + dc] = o;
  }
}

// ---------------------------------------------------------------------------
// Kernel 5: convert the three weight matrices f32 -> bf16 (layout kept [O][K])
// ---------------------------------------------------------------------------
__global__ __launch_bounds__(256)
void convert_w_kernel(const float* __restrict__ w0, int n0, ushort* __restrict__ o0,
                      const float* __restrict__ w1, int n1, ushort* __restrict__ o1,
                      const float* __restrict__ w2, int n2, ushort* __restrict__ o2) {
  const int which = blockIdx.y;
  const float* src = which == 0 ? w0 : which == 1 ? w1 : w2;
  ushort* dst = which == 0 ? o0 : which == 1 ? o1 : o2;
  const int n = which == 0 ? n0 : which == 1 ? n1 : n2;
  const int i = (blockIdx.x * 256 + threadIdx.x) * 4;
  if (i < n) {
    const float4 v = *(const float4*)&src[i];
    ushort4 o;
    o.x = f2bf(v.x); o.y = f2bf(v.y); o.z = f2bf(v.z); o.w = f2bf(v.w);
    *(ushort4*)&dst[i] = o;
  }
}

// ---------------------------------------------------------------------------
// Kernel 6: fully-fused MLP. One block owns a 32-row slab of n.
//   proj = relu(Wp @ xln + pb)          -> LDS (projL, 32x256, swizzled)
//   for hh in {0,1}:
//     h_hh = relu(W1[hh*256:+256] @ [seedT||proj] + b1_hh) -> LDS (hL, 32x256)
//     accO += W2[:, hh*256:+256] @ h_hh   (registers)
//   out = accO + b2   -> fp32 [B][256][S]
// 4 waves; wave w covers o-range [w*64, w*64+64), all 32 s.
// Weights stream per-k-step via global_load_lds (L2-resident, all blocks
// read the same 1.1MB). Intermediate HBM traffic: zero.
// ---------------------------------------------------------------------------
__global__ __launch_bounds__(256)
void fused_mlp_kernel(const ushort* __restrict__ xln,
                      const ushort* __restrict__ seedT,
                      const ushort* __restrict__ wp, const ushort* __restrict__ w1,
                      const ushort* __restrict__ w2,
                      const float* __restrict__ pb, const float* __restrict__ b1,
                      const float* __restrict__ b2, float* __restrict__ out) {
  const int n0 = blockIdx.x * 32;
  const int t = threadIdx.x;
  const int w = t >> 6;
  const int lane = t & 63;
  const int l16 = lane & 15;
  const int quad = lane >> 4;

  __shared__ ushort Wt[256 * 32];        // 16KB  k-step weight tile
  __shared__ ushort Xt[32 * 32];         // 2KB   k-step activation tile
  __shared__ ushort projL[32 * 256];     // 16KB  proj slab (swizzled)
  __shared__ ushort hL[32 * 256];        // 16KB  h half-slab (swizzled)
  __shared__ float biasS[1024];          // 4KB   pb | b1(512) | b2

  biasS[t] = pb[t];
  biasS[256 + t] = b1[t];
  biasS[512 + t] = b1[256 + t];
  biasS[768 + t] = b2[t];

  const f32x4 z = {0.f, 0.f, 0.f, 0.f};

  // ---------------- stage 1: proj = relu(Wp @ xln + pb) ----------------
  {
    f32x4 accP[4][2];
    #pragma unroll
    for (int of = 0; of < 4; ++of) { accP[of][0] = z; accP[of][1] = z; }

    const ushort* xb = xln + (size_t)n0 * C;
    for (int c0 = 0; c0 < C; c0 += 32) {
      __syncthreads();
      #pragma unroll
      for (int q = 0; q < 4; ++q) stage16(wp, C, w * 64 + q * 16, c0, Wt, lane);
      if (w < 2) stage16(xb, C, w * 16, c0, Xt, lane);
      __syncthreads();

      bf16x8 bx[2];
      #pragma unroll
      for (int sf = 0; sf < 2; ++sf) {
        const int sr = sf * 16 + l16;
        bx[sf] = *(const bf16x8*)&Xt[sr * 32 + ((quad ^ (sr & 3)) * 8)];
      }
      #pragma unroll
      for (int of = 0; of < 4; ++of) {
        const int orr = w * 64 + of * 16 + l16;
        const bf16x8 afr = *(const bf16x8*)&Wt[orr * 32 + ((quad ^ (orr & 3)) * 8)];
        accP[of][0] = __builtin_amdgcn_mfma_f32_16x16x32_bf16(afr, bx[0], accP[of][0], 0, 0, 0);
        accP[of][1] = __builtin_amdgcn_mfma_f32_16x16x32_bf16(afr, bx[1], accP[of][1], 0, 0, 0);
      }
    }
    __syncthreads();  // Wt/Xt reads done before epilogue writes projL
    #pragma unroll
    for (int of = 0; of < 4; ++of) {
      #pragma unroll
      for (int sf = 0; sf < 2; ++sf) {
        const int s = sf * 16 + l16;
        const int o = w * 64 + of * 16 + quad * 4;
        ushort4 st;
        st.x = f2bf(fmaxf(accP[of][sf].x + biasS[o + 0], 0.f));
        st.y = f2bf(fmaxf(accP[of][sf].y + biasS[o + 1], 0.f));
        st.z = f2bf(fmaxf(accP[of][sf].z + biasS[o + 2], 0.f));
        st.w = f2bf(fmaxf(accP[of][sf].w + biasS[o + 3], 0.f));
        *(ushort4*)&projL[swz32(s, o >> 3) + (o & 7)] = st;
      }
    }
  }

  // ---------------- stages 2+3, two K-halves ----------------
  f32x4 accO[4][2];
  #pragma unroll
  for (int of = 0; of < 4; ++of) { accO[of][0] = z; accO[of][1] = z; }

  const ushort* stb = seedT + (size_t)n0 * 256;

  for (int hh = 0; hh < 2; ++hh) {
    // stage 2: h_hh = relu(W1[hh*256 : hh*256+256] @ [seedT || proj] + b1_hh)
    f32x4 accH[4][2];
    #pragma unroll
    for (int of = 0; of < 4; ++of) { accH[of][0] = z; accH[of][1] = z; }

    const ushort* w1h = w1 + (size_t)(hh * 256) * 512;
    for (int c0 = 0; c0 < 512; c0 += 32) {
      __syncthreads();
      #pragma unroll
      for (int q = 0; q < 4; ++q) stage16(w1h, 512, w * 64 + q * 16, c0, Wt, lane);
      if (c0 < 256 && w < 2) stage16(stb, 256, w * 16, c0, Xt, lane);
      __syncthreads();

      bf16x8 bx[2];
      if (c0 < 256) {
        #pragma unroll
        for (int sf = 0; sf < 2; ++sf) {
          const int sr = sf * 16 + l16;
          bx[sf] = *(const bf16x8*)&Xt[sr * 32 + ((quad ^ (sr & 3)) * 8)];
        }
      } else {
        #pragma unroll
        for (int sf = 0; sf < 2; ++sf) {
          const int sr = sf * 16 + l16;
          bx[sf] = *(const bf16x8*)&projL[swz32(sr, ((c0 - 256) >> 3) + quad)];
        }
      }
      #pragma unroll
      for (int of = 0; of < 4; ++of) {
        const int orr = w * 64 + of * 16 + l16;
        const bf16x8 afr = *(const bf16x8*)&Wt[orr * 32 + ((quad ^ (orr & 3)) * 8)];
        accH[of][0] = __builtin_amdgcn_mfma_f32_16x16x32_bf16(afr, bx[0], accH[of][0], 0, 0, 0);
        accH[of][1] = __builtin_amdgcn_mfma_f32_16x16x32_bf16(afr, bx[1], accH[of][1], 0, 0, 0);
      }
    }
    __syncthreads();  // hL reads from previous half done; Wt reads done
    #pragma unroll
    for (int of = 0; of < 4; ++of) {
      #pragma unroll
      for (int sf = 0; sf < 2; ++sf) {
        const int s = sf * 16 + l16;
        const int o = w * 64 + of * 16 + quad * 4;
        const float bb0 = biasS[256 + hh * 256 + o];
        ushort4 st;
        st.x = f2bf(fmaxf(accH[of][sf].x + biasS[256 + hh * 256 + o + 0], 0.f));
        st.y = f2bf(fmaxf(accH[of][sf].y + biasS[256 + hh * 256 + o + 1], 0.f));
        st.z = f2bf(fmaxf(accH[of][sf].z + biasS[256 + hh * 256 + o + 2], 0.f));
        st.w = f2bf(fmaxf(accH[of][sf].w + biasS[256 + hh * 256 + o + 3], 0.f));
        (void)bb0;
        *(ushort4*)&hL[swz32(s, o >> 3) + (o & 7)] = st;
      }
    }

    // stage 3: accO += W2[:, hh*256 : +256] @ h_hh
    for (int c0 = 0; c0 < 256; c0 += 32) {
      __syncthreads();
      #pragma unroll
      for (int q = 0; q < 4; ++q)
        stage16(w2 + hh * 256, 512, w * 64 + q * 16, c0, Wt, lane);
      __syncthreads();

      bf16x8 bx[2];
      #pragma unroll
      for (int sf = 0; sf < 2; ++sf) {
        const int sr = sf * 16 + l16;
        bx[sf] = *(const bf16x8*)&hL[swz32(sr, (c0 >> 3) + quad)];
      }
      #pragma unroll
      for (int of = 0; of < 4; ++of) {
        const int orr = w * 64 + of * 16 + l16;
        const bf16x8 afr = *(const bf16x8*)&Wt[orr * 32 + ((quad ^ (orr & 3)) * 8)];
        accO[of][0] = __builtin_amdgcn_mfma_f32_16x16x32_bf16(afr, bx[0], accO[of][0], 0, 0, 0);
        accO[of][1] = __builtin_amdgcn_mfma_f32_16x16x32_bf16(afr, bx[1], accO[of][1], 0, 0, 0);
      }
    }
    __syncthreads();  // hL fully consumed before next half overwrites it
  }

  // ---------------- final epilogue: out fp32 [B][256][S] ----------------
  const int b = n0 >> 10;
  const int sbase = n0 & 1023;
  #pragma unroll
  for (int of = 0; of < 4; ++of) {
    #pragma unroll
    for (int sf = 0; sf < 2; ++sf) {
      const int s = sbase + sf * 16 + l16;
      const int o = w * 64 + of * 16 + quad * 4;
      const float vr[4] = {accO[of][sf].x, accO[of][sf].y,
                           accO[of][sf].z, accO[of][sf].w};
      #pragma unroll
      for (int r = 0; r < 4; ++r)
        out[((size_t)b * 256 + o + r) * S + s] = vr[r] + biasS[768 + o + r];
    }
  }
}

}  // namespace

extern "C" void kernel_launch(void* const* d_in, const int* in_sizes, int n_in,
                              void* d_out, int out_size, void* d_ws, size_t ws_size,
                              hipStream_t stream) {
  const float* seed_xyz  = (const float*)d_in[0];
  const float* p_last    = (const float*)d_in[1];
  const float* f_last    = (const float*)d_in[2];
  const float* seed_feat = (const float*)d_in[3];
  const float* ln_gamma  = (const float*)d_in[4];
  const float* ln_beta   = (const float*)d_in[5];
  const float* proj_w    = (const float*)d_in[6];
  const float* proj_b    = (const float*)d_in[7];
  const float* mlp_w1    = (const float*)d_in[8];
  const float* mlp_b1    = (const float*)d_in[9];
  const float* mlp_w2    = (const float*)d_in[10];
  const float* mlp_b2    = (const float*)d_in[11];
  float* out = (float*)d_out;

  // workspace layout:
  //   0      +64KB   idx
  //   64KB   +64KB   sIdx
  //   128KB  +64KB   sS
  //   256KB  +384KB  proj_w bf16 [256][768]
  //   640KB  +512KB  mlp_w1 bf16 [512][512]
  //   1152KB +256KB  mlp_w2 bf16 [256][512]
  //   2MB    +24MB   tmp   bf16 [16384][768]  (gathered, pre-LN)
  //   26MB   +24MB   xln   bf16 [16384][768]
  //   50MB   +8MB    seedT bf16 [16384][256]
  char* ws = (char*)d_ws;
  int*    idx   = (int*)(ws);
  int*    sIdx  = (int*)(ws + (64 << 10));
  int*    sS    = (int*)(ws + (128 << 10));
  ushort* wp_bf = (ushort*)(ws + (256 << 10));
  ushort* w1_bf = (ushort*)(ws + (640 << 10));
  ushort* w2_bf = (ushort*)(ws + (1152 << 10));
  ushort* tmp   = (ushort*)(ws + (2ull << 20));
  ushort* xln   = (ushort*)(ws + (26ull << 20));
  ushort* seedT = (ushort*)(ws + (50ull << 20));

  nn_kernel<<<dim3(S / 16, B), 256, 0, stream>>>(seed_xyz, p_last, idx);
  sort_kernel<<<dim3(B), 512, 0, stream>>>(idx, sIdx, sS);

  gatherT_kernel<<<dim3(M / 64, B), 256, 0, stream>>>(f_last, sIdx, sS, tmp);
  ln_kernel<<<dim3(1024, B), 256, 0, stream>>>(tmp, ln_gamma, ln_beta, xln);

  transpose_sf_kernel<<<dim3(S / 64, D / 64, B), 256, 0, stream>>>(seed_feat, seedT);
  convert_w_kernel<<<dim3(256, 3), 256, 0, stream>>>(
      proj_w, D * C, wp_bf, mlp_w1, 512 * 512, w1_bf, mlp_w2, 256 * 512, w2_bf);

  fused_mlp_kernel<<<dim3(N / 32), 256, 0, stream>>>(
      xln, seedT, wp_bf, w1_bf, w2_bf, proj_b, mlp_b1, mlp_b2, out);
}